// Round 9
// baseline (325.013 us; speedup 1.0000x reference)
//
#include <hip/hip_runtime.h>
#include <hip/hip_bf16.h>
#include <stdint.h>

#define HF 256   // H == F == 256
#define GG 50    // G
#define LOG2E 1.44269504088896341f
#define LN2   0.69314718055994531f

typedef __attribute__((ext_vector_type(8))) short bf16x8;
typedef __attribute__((ext_vector_type(4))) short bf16x4;
typedef __attribute__((ext_vector_type(4))) float f32x4;

// packed f32x2 -> bf16x2 (v_cvt_pk_bf16_f32 on gfx950), low short = a
__device__ __forceinline__ uint32_t f2bf2u(float a, float b){
    __hip_bfloat162 h = __float22bfloat162_rn(make_float2(a, b));
    union { __hip_bfloat162 h; uint32_t u; } v; v.h = h; return v.u;
}
__device__ __forceinline__ float bf2f(short s){
    union { uint32_t u; float f; } v; v.u = ((uint32_t)(uint16_t)s) << 16;
    return v.f;
}

// ---------------------------------------------------------------------------
// prep_kernel: [pack weights, pre-scaled for ssp folding] + [b2p colsum] +
// [x fp32->bf16] + [degree histogram] + [agg=0]
// Folding: ssp(x) = ln2*log2(1+exp2(x*log2e)) - ln2. Bake log2e into w1 (and
// its bias row), ln2 into w2, and b2p = b2 - colsum(bf16(ln2*w2)). The edge
// kernel's ssp is then just {exp2, add 1, log2} and GEMM2's -ln2 shift lands
// in b2p. Same trick for lin2 in node2.
// B-frag (ntg, kt): lane l holds B[k=kt*32+(l>>4)*8+j][n=ntg*16+(l&15)].
// 8-wave hid perm: pi'(s) = (s>>5)*32 + (s&1)*16 + ((s&31)>>1)
// ---------------------------------------------------------------------------
__device__ __forceinline__ void pack_natural(const float* __restrict__ B,
                                             short* __restrict__ Bp,
                                             int idx, int KT, int kmax, float scale)
{
    int lane = idx & 63;
    int kt   = (idx >> 6) & (KT - 1);
    int ntg  = idx >> (6 + (KT == 2 ? 1 : 3));
    int col  = ntg * 16 + (lane & 15);
    int k0   = kt * 32 + (lane >> 4) * 8;
    uint32_t u[4];
#pragma unroll
    for (int jj = 0; jj < 4; ++jj) {
        int ka = k0 + 2*jj, kb = ka + 1;
        float a = (ka < kmax) ? B[(size_t)ka * HF + col] * scale : 0.f;
        float b = (kb < kmax) ? B[(size_t)kb * HF + col] * scale : 0.f;
        u[jj] = f2bf2u(a, b);
    }
    *(uint4*)&Bp[(size_t)idx * 8] = *(uint4*)u;
}

__global__ __launch_bounds__(256)
void prep_kernel(const float* __restrict__ w1, const float* __restrict__ b1,
                 const float* __restrict__ w2, const float* __restrict__ b2,
                 const float* __restrict__ lin1, const float* __restrict__ lin2,
                 short* __restrict__ w1p, short* __restrict__ w2p,
                 short* __restrict__ lin1p, short* __restrict__ lin2p,
                 float* __restrict__ b2p,
                 const float* __restrict__ x, short* __restrict__ x_bf, int nx8,
                 const int* __restrict__ eidx, int* __restrict__ cnt, int E,
                 float* __restrict__ agg, int nAgg4, int gConv, int gHist)
{
    int b = blockIdx.x, tid = threadIdx.x;
    if (b < 8) {                       // w1p * log2e, with b1*log2e at k==GG
        int idx  = b * 256 + tid;
        int lane = idx & 63;
        int kt   = (idx >> 6) & 1;
        int ntg  = idx >> 7;
        int col  = ntg * 16 + (lane & 15);
        int k0   = kt * 32 + (lane >> 4) * 8;
        uint32_t u[4];
#pragma unroll
        for (int jj = 0; jj < 4; ++jj) {
            int ka = k0 + 2*jj, kb = ka + 1;
            float va = (ka < GG) ? w1[(size_t)ka * HF + col] * LOG2E
                                 : ((ka == GG) ? b1[col] * LOG2E : 0.f);
            float vb = (kb < GG) ? w1[(size_t)kb * HF + col] * LOG2E
                                 : ((kb == GG) ? b1[col] * LOG2E : 0.f);
            u[jj] = f2bf2u(va, vb);
        }
        *(uint4*)&w1p[(size_t)idx * 8] = *(uint4*)u;
    } else if (b < 40) {               // w2p * ln2, permuted k axis (8-wave pi')
        int idx = (b - 8) * 256 + tid;
        int lane = idx & 63;
        int kt   = (idx >> 6) & 7;
        int ntg  = idx >> 9;
        int col  = ntg * 16 + (lane & 15);
        int s0   = kt * 32 + (lane >> 4) * 8;
        uint32_t u[4];
#pragma unroll
        for (int jj = 0; jj < 4; ++jj) {
            int sa = s0 + 2*jj, sb = sa + 1;
            int fa = (sa >> 5) * 32 + (sa & 1) * 16 + ((sa & 31) >> 1);
            int fb = (sb >> 5) * 32 + (sb & 1) * 16 + ((sb & 31) >> 1);
            u[jj] = f2bf2u(w2[(size_t)fa * HF + col] * LN2,
                           w2[(size_t)fb * HF + col] * LN2);
        }
        *(uint4*)&w2p[(size_t)idx * 8] = *(uint4*)u;
    } else if (b < 72) {
        pack_natural(lin1, lin1p, (b - 40) * 256 + tid, 8, HF, 1.0f);
    } else if (b < 104) {              // lin2 * log2e (node2 ssp fold)
        pack_natural(lin2, lin2p, (b - 72) * 256 + tid, 8, HF, LOG2E);
    } else if (b == 104) {             // b2p[f] = b2[f] - sum_k bf16(ln2*w2[k][f])
        int f = tid;
        float s = 0.f;
        for (int k = 0; k < HF; ++k) {
            uint32_t r = f2bf2u(w2[(size_t)k * HF + f] * LN2, 0.f);
            s += bf2f((short)(r & 0xFFFF));
        }
        b2p[f] = b2[f] - s;
    } else if (b < 105 + gConv) {      // x -> bf16, 8 elems/thread
        int idx = (b - 105) * 256 + tid;
        if (idx < nx8) {
            const float* xp = x + (size_t)idx * 8;
            float4 p0 = *(const float4*)(xp);
            float4 p1 = *(const float4*)(xp + 4);
            uint32_t u[4] = { f2bf2u(p0.x, p0.y), f2bf2u(p0.z, p0.w),
                              f2bf2u(p1.x, p1.y), f2bf2u(p1.z, p1.w) };
            *(uint4*)&x_bf[(size_t)idx * 8] = *(uint4*)u;
        }
    } else if (b < 105 + gConv + gHist) {   // histogram
        int e = (b - 105 - gConv) * 256 + tid;
        if (e < E) atomicAdd(&cnt[eidx[e]], 1);
    } else {                           // agg zero (float4 granular)
        int idx = (b - 105 - gConv - gHist) * 256 + tid;
        if (idx < nAgg4) ((float4*)agg)[idx] = make_float4(0.f, 0.f, 0.f, 0.f);
    }
}

// ---------------------------------------------------------------------------
// scan_gemm_kernel: block 0 = serial exclusive scan (latency-bound; hides
// under the GEMM); blocks 1.. = y_p GEMM, N-split (rows x 128-feature half)
// for 2x grid coverage of the latency-bound small GEMM.
// y_p stays in the 4-wave pi layout: true f -> s = (f>>6)*64+(f&15)*4+((f>>4)&3)
// ---------------------------------------------------------------------------
__global__ __launch_bounds__(256)
void scan_gemm_kernel(const int* __restrict__ cnt, int* __restrict__ row,
                      int* __restrict__ cursor, int N, int E,
                      const short* __restrict__ x_bf, const short* __restrict__ lin1p,
                      short* __restrict__ y_p)
{
    const int tid = threadIdx.x;
    if (blockIdx.x == 0) {             // ---- scan
        __shared__ int part[256];
        const int CH = (N + 255) / 256;
        int lo = tid * CH;
        int hi = min(lo + CH, N);
        int s = 0;
        for (int n = lo; n < hi; ++n) s += cnt[n];
        part[tid] = s;
        __syncthreads();
        for (int off = 1; off < 256; off <<= 1) {
            int v = (tid >= off) ? part[tid - off] : 0;
            __syncthreads();
            part[tid] += v;
            __syncthreads();
        }
        int acc = part[tid] - s;   // exclusive
        for (int n = lo; n < hi; ++n) {
            row[n] = acc; cursor[n] = acc;
            acc += cnt[n];
        }
        if (tid == 255) row[N] = E;
        return;
    }
    // ---- y_p GEMM: block covers rows [rowblk*64, +64) x features [fh*128, +128)
    const int blk    = blockIdx.x - 1;
    const int rowblk = blk >> 1;
    const int fh     = blk & 1;
    const int lane = tid & 63;
    const int w    = tid >> 6;
    const int l15  = lane & 15;
    const int quad = lane >> 4;
    const int row0 = rowblk * 64;

    f32x4 acc[4][2];
#pragma unroll
    for (int mt = 0; mt < 4; ++mt)
#pragma unroll
        for (int nt = 0; nt < 2; ++nt) acc[mt][nt] = (f32x4){0.f,0.f,0.f,0.f};

#pragma unroll 2
    for (int kt = 0; kt < 8; ++kt) {
        bf16x8 af[4];
#pragma unroll
        for (int mt = 0; mt < 4; ++mt) {
            int r = row0 + mt * 16 + l15;
            int rl = (r < N) ? r : 0;
            af[mt] = *(const bf16x8*)&x_bf[(size_t)rl * HF + kt * 32 + quad * 8];
        }
#pragma unroll
        for (int nt = 0; nt < 2; ++nt) {
            int ntg = fh * 8 + w * 2 + nt;
            bf16x8 bfr = *(const bf16x8*)&lin1p[(size_t)((ntg*8+kt)*64+lane)*8];
#pragma unroll
            for (int mt = 0; mt < 4; ++mt)
                acc[mt][nt] = __builtin_amdgcn_mfma_f32_16x16x32_bf16(af[mt], bfr, acc[mt][nt], 0, 0, 0);
        }
    }
    // true features: f = fh*128 + w*32 + nt*16 + l15 -> s = w4*64 + l15*4 + nt4
    const int sbase = (fh * 2 + (w >> 1)) * 64 + l15 * 4 + (w & 1) * 2;
#pragma unroll
    for (int mt = 0; mt < 4; ++mt) {
#pragma unroll
        for (int r = 0; r < 4; ++r) {
            int row_ = row0 + mt * 16 + quad * 4 + r;
            if (row_ < N) {
                *(uint32_t*)&y_p[(size_t)row_ * HF + sbase] =
                    f2bf2u(acc[mt][0][r], acc[mt][1][r]);
            }
        }
    }
}

// ---------------------------------------------------------------------------
// scatter_kernel: counting-sort scatter using cursor from the scan
// ---------------------------------------------------------------------------
__global__ __launch_bounds__(256)
void scatter_kernel(const int* __restrict__ eidx, int* __restrict__ cursor,
                    int* __restrict__ perm, int E)
{
    int e = blockIdx.x * 256 + threadIdx.x;
    if (e < E) {
        int pos = atomicAdd(&cursor[eidx[e]], 1);
        perm[pos] = e;
    }
}

// ---------------------------------------------------------------------------
// node2_kernel: out = ssp(agg@lin2 + b) + x, N-split (rows x 128-feat half).
// lin2p pre-scaled by log2e; out = fma(ln2, log2(1+exp2(z)), x - ln2).
// ---------------------------------------------------------------------------
__global__ __launch_bounds__(256)
void node2_kernel(const float* __restrict__ agg, const short* __restrict__ lin2p,
                  const float* __restrict__ bias, const float* __restrict__ x,
                  float* __restrict__ out, int N)
{
    const int tid  = threadIdx.x;
    const int lane = tid & 63;
    const int w    = tid >> 6;
    const int l15  = lane & 15;
    const int quad = lane >> 4;
    const int row0 = ((int)blockIdx.x >> 1) * 64;
    const int fh   = blockIdx.x & 1;

    f32x4 acc[4][2];
#pragma unroll
    for (int mt = 0; mt < 4; ++mt)
#pragma unroll
        for (int nt = 0; nt < 2; ++nt) acc[mt][nt] = (f32x4){0.f,0.f,0.f,0.f};

#pragma unroll 2
    for (int kt = 0; kt < 8; ++kt) {
        bf16x8 af[4];
#pragma unroll
        for (int mt = 0; mt < 4; ++mt) {
            int r = row0 + mt * 16 + l15;
            int rl = (r < N) ? r : 0;
            const float* ap = agg + (size_t)rl * HF + kt * 32 + quad * 8;
            float4 p0 = *(const float4*)(ap);
            float4 p1 = *(const float4*)(ap + 4);
            union { uint32_t u[4]; bf16x8 v; } c;
            c.u[0] = f2bf2u(p0.x, p0.y); c.u[1] = f2bf2u(p0.z, p0.w);
            c.u[2] = f2bf2u(p1.x, p1.y); c.u[3] = f2bf2u(p1.z, p1.w);
            af[mt] = c.v;
        }
#pragma unroll
        for (int nt = 0; nt < 2; ++nt) {
            int ntg = fh * 8 + w * 2 + nt;
            bf16x8 bfr = *(const bf16x8*)&lin2p[(size_t)((ntg*8+kt)*64+lane)*8];
#pragma unroll
            for (int mt = 0; mt < 4; ++mt)
                acc[mt][nt] = __builtin_amdgcn_mfma_f32_16x16x32_bf16(af[mt], bfr, acc[mt][nt], 0, 0, 0);
        }
    }
    float bs[2];
#pragma unroll
    for (int nt = 0; nt < 2; ++nt)
        bs[nt] = LOG2E * bias[fh * 128 + w * 32 + nt * 16 + l15];
#pragma unroll
    for (int mt = 0; mt < 4; ++mt) {
#pragma unroll
        for (int r = 0; r < 4; ++r) {
            int row = row0 + mt * 16 + quad * 4 + r;
            if (row < N) {
#pragma unroll
                for (int nt = 0; nt < 2; ++nt) {
                    int f = fh * 128 + w * 32 + nt * 16 + l15;
                    float z = acc[mt][nt][r] + bs[nt];
                    float g = __builtin_amdgcn_logf(1.f + __builtin_amdgcn_exp2f(z));
                    float xv = x[(size_t)row * HF + f];
                    out[(size_t)row * HF + f] = fmaf(LN2, g, xv - LN2);
                }
            }
        }
    }
}

// ---------------------------------------------------------------------------
// edge_mfma: 8 waves x 32-feature slices over a 64-edge tile (512 threads).
// LB(512,6): 85 regs/wave cap -> 3 blocks/CU = 24 waves/CU, no spill (R8:
// VGPR 40, WRITE 44 MB, occ 60%). VALU diet this round: division-free staging
// (64x32 dword-slots = 4x512 exactly) and 3-op ssp (weights pre-scaled).
//   GEMM1: z = ea @ (log2e*w1) [+ log2e*b1 via k=50 row]; hid = log2(1+2^z)
//   GEMM2: W = hid @ (ln2*w2, pi'-perm k); msg = (W+b2p)*C*y -> msgT
//   GEMM3: segment-sum via selection matrix; per-run f4 stores / atomics
// ---------------------------------------------------------------------------
__global__ __launch_bounds__(512, 6)
void edge_mfma(const float* __restrict__ ea, const int* __restrict__ eidx,
               const float* __restrict__ ew,
               const short* __restrict__ w1p,
               const short* __restrict__ w2p, const float* __restrict__ b2p,
               const short* __restrict__ y_p, const int* __restrict__ perm,
               const int* __restrict__ rowp,
               float* __restrict__ agg, int E)
{
    __shared__ short smem[19584];      // 39168 B
    short* ea_b = smem;                // [64][72]   (stage + GEMM1 reads)
    short* hid  = smem;                // [64][264]  (aliases ea_b; barrier-split)
    short* msgT = smem;                // [256][72]  (phase 4+, aliases)
    short* St   = smem + 18432;        // [16][72]
    __shared__ int s_e[64], s_j[64];
    __shared__ float s_c[64];
    __shared__ int s_runnode[64];
    __shared__ unsigned char s_runcomp[64];
    __shared__ unsigned long long s_bmask;
    __shared__ int s_runcnt;

    const int tid  = threadIdx.x;
    const int lane = tid & 63;
    const int w    = tid >> 6;         // 0..7
    const int l15  = lane & 15;
    const int quad = lane >> 4;
    const int e0   = blockIdx.x * 64;

    if (tid < 64) {
        int pp = e0 + tid;
        int e = 0, iv = -1, jv = 0;
        float c = 0.f;
        if (pp < E) {
            e  = perm[pp];
            iv = eidx[e];
            jv = eidx[E + e];
            float d0 = ew[e*3+0], d1 = ew[e*3+1], d2 = ew[e*3+2];
            float d = sqrtf(d0*d0 + d1*d1 + d2*d2);
            c = (d <= 2.0f) ? 0.5f * (__cosf(d * 1.57079632679489662f) + 1.0f) : 0.f;
        }
        s_e[tid] = e; s_j[tid] = jv; s_c[tid] = c;
        int ivn = __shfl_down(iv, 1);
        bool flag = (tid == 63) || (iv != ivn);     // run ends at tid
        unsigned long long m = __ballot(flag);
        if (flag) {
            int rid = (int)__popcll(m & ((1ull << tid) - 1ull));
            s_runnode[rid] = iv;
            int comp = 0;
            if (iv >= 0) {
                int lo = rowp[iv], hi = rowp[iv + 1];
                comp = (lo >= e0 && hi <= e0 + 64) ? 1 : 0;
            }
            s_runcomp[rid] = (unsigned char)comp;
        }
        if (tid == 0) { s_bmask = m; s_runcnt = (int)__popcll(m); }
    }
    __syncthreads();

    // stage edge_attr: 64 edges x 32 dword-slots = 2048 = 4x512 (no division)
    // q<25: float2 -> bf16x2; q==25: shorts 50,51 = {1.0 bias row, 0}; q>25: 0
#pragma unroll
    for (int i = 0; i < 4; ++i) {
        int idx = i * 512 + tid;
        int e = idx >> 5, q = idx & 31;
        uint32_t val;
        if (q < 25) {
            float2 v = *(const float2*)(ea + (size_t)s_e[e] * GG + q * 2);
            val = f2bf2u(v.x, v.y);
        } else {
            val = (q == 25) ? 0x00003F80u : 0u;
        }
        *(uint32_t*)&ea_b[e * 72 + q * 2] = val;
    }
    __syncthreads();

    // ---- GEMM1: [64e x 64k] @ [64k x 32f-slice]  (B pre-scaled by log2e)
    f32x4 acc1[4][2];
#pragma unroll
    for (int mt = 0; mt < 4; ++mt)
#pragma unroll
        for (int nt = 0; nt < 2; ++nt) acc1[mt][nt] = (f32x4){0.f,0.f,0.f,0.f};

#pragma unroll
    for (int kt = 0; kt < 2; ++kt) {
        bf16x8 af[4];
#pragma unroll
        for (int mt = 0; mt < 4; ++mt)
            af[mt] = *(bf16x8*)&ea_b[(mt * 16 + l15) * 72 + kt * 32 + quad * 8];
#pragma unroll
        for (int nt = 0; nt < 2; ++nt) {
            bf16x8 bfr = *(const bf16x8*)&w1p[(size_t)(((w*2+nt)*2+kt)*64+lane)*8];
#pragma unroll
            for (int mt = 0; mt < 4; ++mt)
                acc1[mt][nt] = __builtin_amdgcn_mfma_f32_16x16x32_bf16(af[mt], bfr, acc1[mt][nt], 0, 0, 0);
        }
    }
    __syncthreads();   // ea_b dead; hid (aliased) may be written

    // hid = log2(1 + exp2(z))  (3-op folded ssp)
#pragma unroll
    for (int mt = 0; mt < 4; ++mt) {
#pragma unroll
        for (int r = 0; r < 4; ++r) {
            int e = mt * 16 + quad * 4 + r;
            float g0 = __builtin_amdgcn_logf(1.f + __builtin_amdgcn_exp2f(acc1[mt][0][r]));
            float g1 = __builtin_amdgcn_logf(1.f + __builtin_amdgcn_exp2f(acc1[mt][1][r]));
            *(uint32_t*)&hid[e * 264 + w * 32 + l15 * 2] = f2bf2u(g0, g1);
        }
    }
    __syncthreads();

    // ---- GEMM2: [64e x 256k(pi')] @ [256k x 32f-slice]  (B pre-scaled by ln2)
    f32x4 acc2[4][2];
#pragma unroll
    for (int mt = 0; mt < 4; ++mt)
#pragma unroll
        for (int nt = 0; nt < 2; ++nt) acc2[mt][nt] = (f32x4){0.f,0.f,0.f,0.f};

    __builtin_amdgcn_s_setprio(1);
#pragma unroll 1
    for (int kt = 0; kt < 8; ++kt) {
        bf16x8 af[4];
#pragma unroll
        for (int mt = 0; mt < 4; ++mt)
            af[mt] = *(bf16x8*)&hid[(mt * 16 + l15) * 264 + kt * 32 + quad * 8];
#pragma unroll
        for (int nt = 0; nt < 2; ++nt) {
            bf16x8 bfr = *(const bf16x8*)&w2p[(size_t)(((w*2+nt)*8+kt)*64+lane)*8];
#pragma unroll
            for (int mt = 0; mt < 4; ++mt)
                acc2[mt][nt] = __builtin_amdgcn_mfma_f32_16x16x32_bf16(af[mt], bfr, acc2[mt][nt], 0, 0, 0);
        }
    }
    __builtin_amdgcn_s_setprio(0);

    // ---- y_p gather (after GEMM2: frees regs across peak; drains over barrier)
    uint32_t yv[4][4];
    const int ypos = (w >> 1) * 64 + l15 * 4 + (w & 1) * 2;
#pragma unroll
    for (int mt = 0; mt < 4; ++mt)
#pragma unroll
        for (int r = 0; r < 4; ++r) {
            int e = mt * 16 + quad * 4 + r;
            yv[mt][r] = *(const uint32_t*)&y_p[(size_t)s_j[e] * HF + ypos];
        }
    float bias2[2];
#pragma unroll
    for (int nt = 0; nt < 2; ++nt) bias2[nt] = b2p[w * 32 + nt * 16 + l15];

    __syncthreads();   // hid dead; msgT/St may now overwrite

    // ---- msg epilogue -> msgT[col][e] (stride 72)
#pragma unroll
    for (int mt = 0; mt < 4; ++mt) {
        float c0 = s_c[mt * 16 + quad * 4 + 0];
        float c1 = s_c[mt * 16 + quad * 4 + 1];
        float c2 = s_c[mt * 16 + quad * 4 + 2];
        float c3 = s_c[mt * 16 + quad * 4 + 3];
#pragma unroll
        for (int nt = 0; nt < 2; ++nt) {
            int col = w * 32 + nt * 16 + l15;
            float y0 = bf2f((short)(nt ? (yv[mt][0] >> 16) : (yv[mt][0] & 0xFFFF)));
            float y1 = bf2f((short)(nt ? (yv[mt][1] >> 16) : (yv[mt][1] & 0xFFFF)));
            float y2 = bf2f((short)(nt ? (yv[mt][2] >> 16) : (yv[mt][2] & 0xFFFF)));
            float y3 = bf2f((short)(nt ? (yv[mt][3] >> 16) : (yv[mt][3] & 0xFFFF)));
            float v0 = (acc2[mt][nt][0] + bias2[nt]) * c0 * y0;
            float v1 = (acc2[mt][nt][1] + bias2[nt]) * c1 * y1;
            float v2 = (acc2[mt][nt][2] + bias2[nt]) * c2 * y2;
            float v3 = (acc2[mt][nt][3] + bias2[nt]) * c3 * y3;
            uint2 u = make_uint2(f2bf2u(v0, v1), f2bf2u(v2, v3));
            *(uint2*)&msgT[col * 72 + mt * 16 + quad * 4] = u;
        }
    }
    // build S^T[run-local][edge] for run group 0
    {
        unsigned long long bm = s_bmask;
        int e   = tid & 63;
        int rb  = tid >> 6;
        int rid = (int)__popcll(bm & ((1ull << e) - 1ull));
#pragma unroll
        for (int q = 0; q < 2; ++q) {
            int r = rb + q * 8;
            St[r * 72 + e] = (rid == r) ? (short)0x3F80 : (short)0;
        }
    }
    __syncthreads();

    // ---- GEMM3: O[feature][run] = msgT @ S^T, then flush per run
    const int runcnt = s_runcnt;
    for (int ntg = 0; ntg * 16 < runcnt; ++ntg) {
        if (ntg > 0) {   // rare: >16 runs in a tile
            __syncthreads();
            unsigned long long bm = s_bmask;
            int e   = tid & 63;
            int rb  = tid >> 6;
            int rid = (int)__popcll(bm & ((1ull << e) - 1ull));
#pragma unroll
            for (int q = 0; q < 2; ++q) {
                int r = rb + q * 8;
                St[r * 72 + e] = (rid == ntg * 16 + r) ? (short)0x3F80 : (short)0;
            }
            __syncthreads();
        }
        f32x4 acc3[2];
#pragma unroll
        for (int mt = 0; mt < 2; ++mt) acc3[mt] = (f32x4){0.f,0.f,0.f,0.f};
#pragma unroll
        for (int kt = 0; kt < 2; ++kt) {
            bf16x8 bS = *(bf16x8*)&St[l15 * 72 + kt * 32 + quad * 8];
#pragma unroll
            for (int mt = 0; mt < 2; ++mt) {
                bf16x8 af = *(bf16x8*)&msgT[(w*32 + mt*16 + l15) * 72 + kt*32 + quad*8];
                acc3[mt] = __builtin_amdgcn_mfma_f32_16x16x32_bf16(af, bS, acc3[mt], 0, 0, 0);
            }
        }
        // lane owns run r = ntg*16 + l15; features f = w*32 + mt*16 + quad*4 + g
        int r = ntg * 16 + l15;
        if (r < runcnt) {
            int node = s_runnode[r];
            if (node >= 0) {
                float* ap = agg + (size_t)node * HF + w * 32 + quad * 4;
                if (s_runcomp[r]) {
#pragma unroll
                    for (int mt = 0; mt < 2; ++mt) {
                        float4 v = make_float4(acc3[mt][0], acc3[mt][1], acc3[mt][2], acc3[mt][3]);
                        *(float4*)(ap + mt * 16) = v;
                    }
                } else {
#pragma unroll
                    for (int mt = 0; mt < 2; ++mt)
#pragma unroll
                        for (int g = 0; g < 4; ++g)
                            atomicAdd(ap + mt * 16 + g, acc3[mt][g]);
                }
            }
        }
    }
}

// ---------------------------------------------------------------------------
extern "C" void kernel_launch(void* const* d_in, const int* in_sizes, int n_in,
                              void* d_out, int out_size, void* d_ws, size_t ws_size,
                              hipStream_t stream)
{
    const float* x     = (const float*)d_in[0];
    const int*   eidx  = (const int*)  d_in[1];
    const float* ew    = (const float*)d_in[2];
    const float* ea    = (const float*)d_in[3];
    const float* w1    = (const float*)d_in[4];
    const float* b1    = (const float*)d_in[5];
    const float* w2    = (const float*)d_in[6];
    const float* b2    = (const float*)d_in[7];
    const float* lin1  = (const float*)d_in[8];
    const float* lin2  = (const float*)d_in[9];
    const float* lin2b = (const float*)d_in[10];
    float* out = (float*)d_out;

    const int N = in_sizes[0] / HF;
    const int E = in_sizes[2] / 3;

    const size_t fN = (size_t)N * HF;
    float* agg    = (float*)d_ws;                    // N*256 f32
    short* y_p    = (short*)(agg + fN);              // N*256 bf16 (pi-permuted)
    short* x_bf   = y_p + fN;                        // N*256 bf16
    int*   cnt    = (int*)(x_bf + fN);
    int*   row    = cnt + N;                         // N+1
    int*   cursor = row + (N + 8);
    int*   perm   = cursor + N;
    short* w1p    = (short*)(((uintptr_t)(perm + E) + 255) & ~(uintptr_t)255);
    short* w2p    = w1p + 16384;                     // 32 KB / 128 KB
    short* lin1p  = w2p + 65536;
    short* lin2p  = lin1p + 65536;
    float* b2p    = (float*)(lin2p + 65536);         // 256 f32

    hipMemsetAsync(cnt, 0, (size_t)N * sizeof(int), stream);

    const int nx8   = (int)(fN / 8);
    const int nAgg4 = (int)(fN / 4);
    const int gConv = (nx8 + 255) / 256;
    const int gHist = (E + 255) / 256;
    const int gZero = (nAgg4 + 255) / 256;
    prep_kernel<<<dim3(105 + gConv + gHist + gZero), dim3(256), 0, stream>>>(
        w1, b1, w2, b2, lin1, lin2, w1p, w2p, lin1p, lin2p, b2p,
        x, x_bf, nx8, eidx, cnt, E, agg, nAgg4, gConv, gHist);

    const int gNode = (N + 63) / 64;
    scan_gemm_kernel<<<dim3(1 + 2 * gNode), dim3(256), 0, stream>>>(
        cnt, row, cursor, N, E, x_bf, lin1p, y_p);

    const int gScatter = (E + 255) / 256;
    scatter_kernel<<<dim3(gScatter), dim3(256), 0, stream>>>(eidx, cursor, perm, E);

    edge_mfma<<<dim3((E + 63) / 64), dim3(512), 0, stream>>>(
        ea, eidx, ew, w1p, w2p, b2p, y_p, perm, row, agg, E);

    node2_kernel<<<dim3(2 * gNode), dim3(256), 0, stream>>>(
        agg, lin2p, lin2b, x, out, N);
}